// Round 8
// baseline (186.039 us; speedup 1.0000x reference)
//
#include <hip/hip_runtime.h>
#include <math.h>

#define NN 20000
#define NE 320000
#define TP 12
#define OC 256
#define HIDN 128
#define OD 12
#define FT 48            // FIN*TP
#define CAP 64           // ELL row capacity (deg ~Poisson(16); P(>64) negligible)
#define NG 8             // nodes per block, gate kernel
#define NM 16            // nodes per block, mlp kernel
#define LOG2E 1.44269504088896340736f

#define NB_E    ((NE + 255) / 256)         // 1250
#define NB_XT   ((NN * TP + 255) / 256)    // 938
#define NB_DINV ((NN + 255) / 256)         // 79

// ---- workspace layout (float indices) ----
#define OFF_CNT    0                        // int[NN]
#define OFF_DEG    (OFF_CNT + NN)           // float[NN]
#define OFF_DINV   (OFF_DEG + NN)           // float[NN]
#define OFF_MZ     (OFF_DINV + NN)          // float[4*OC], pre-scaled log2e
#define OFF_MH     (OFF_MZ + 4*OC)          // float[4*OC], pre-scaled 2*log2e
#define OFF_CZ     (OFF_MH + 4*OC)
#define OFF_CH     (OFF_CZ + OC)
#define OFF_PROBS  (OFF_CH + OC)
#define OFF_W2T    (OFF_PROBS + 16)         // [k][j] 12x128
#define OFF_ELL    (OFF_W2T + HIDN*OD)      // float2[NN*CAP] {src,nrm} | tierB: P
#define OFF_P      (OFF_ELL + 2*NN*CAP)     // float4[NN*TP]
#define OFF_XT     (OFF_P + NN*FT)          // float4[NN*TP]
#define NEED_ELL   ((size_t)(OFF_XT) * 4)              // ELL + P, no XT
#define NEED_XT    ((size_t)(OFF_XT + NN*FT) * 4)      // everything

// ---- per-wave int64/int32 detection ----
__device__ __forceinline__ int detect64(const void* ei) {
    const unsigned long long* p = (const unsigned long long*)ei;
    unsigned long long v = p[threadIdx.x & 63];
    return (__ballot(v < (unsigned long long)NN) == ~0ull) ? 1 : 0;
}

__device__ __forceinline__ int load_idx(const void* ei, int is64, long off) {
    return is64 ? (int)((const long long*)ei)[off] : ((const int*)ei)[off];
}

__device__ __forceinline__ float4 load_xrow(const float4* __restrict__ XT4,
                                            const float* __restrict__ x,
                                            int useXT, int n, int t) {
    if (useXT) return XT4[n * TP + t];
    const float* xb = x + n * FT + t;
    return make_float4(xb[0], xb[12], xb[24], xb[36]);
}

// ---- K1: single-pass ELL build (deg + cnt + records); extra blocks: x -> XT ----
__global__ __launch_bounds__(256) void build_kernel(
    const void* ei, const float* __restrict__ w, const float* __restrict__ x,
    int* __restrict__ cnt, float* __restrict__ deg, float2* __restrict__ ell,
    float4* __restrict__ XT4, int useELL, int useXT) {
    int bid = blockIdx.x;
    if (bid < NB_E) {
        int is64 = detect64(ei);
        int e = bid * 256 + threadIdx.x;
        if (e < NE) {
            int src = load_idx(ei, is64, e);
            int dst = load_idx(ei, is64, (long)NE + e);
            float we = w[e];
            atomicAdd(&deg[dst], we);
            if (useELL) {
                int slot = atomicAdd(&cnt[dst], 1);
                if (slot < CAP)
                    ell[dst * CAP + slot] = make_float2(__int_as_float(src), we);
            }
        }
    } else if (useXT) {
        int idx = (bid - NB_E) * 256 + threadIdx.x;
        if (idx < NN * TP) {
            int n = idx / TP;
            int t = idx - n * TP;
            const float* xb = x + n * FT + t;
            XT4[idx] = make_float4(xb[0], xb[12], xb[24], xb[36]);
        }
    }
}

// ---- K2: blocks 0..78 dinv; 79 weight fold + probs; 80 W2T ----
__global__ __launch_bounds__(256) void prep_kernel(
    const float* __restrict__ deg, float* __restrict__ dinv,
    const float* __restrict__ Wz, const float* __restrict__ bz,
    const float* __restrict__ Wh, const float* __restrict__ bh,
    const float* __restrict__ Lzw, const float* __restrict__ Lzb,
    const float* __restrict__ Lhw, const float* __restrict__ Lhb,
    const float* __restrict__ att, const float* __restrict__ W2,
    float* __restrict__ Mz, float* __restrict__ Mh,
    float* __restrict__ cz, float* __restrict__ ch,
    float* __restrict__ probs, float* __restrict__ W2T) {
    int bid = blockIdx.x;
    int tid = threadIdx.x;
    if (bid < NB_DINV) {
        int n = bid * 256 + tid;
        if (n < NN) dinv[n] = 1.0f / sqrtf(deg[n] + 1.0f);   // + self-loop weight
    } else if (bid == NB_DINV) {
        int c = tid;
        float az0 = 0, az1 = 0, az2 = 0, az3 = 0, abz = 0;
        float ah0 = 0, ah1 = 0, ah2 = 0, ah3 = 0, abh = 0;
        for (int k = 0; k < OC; ++k) {
            float lz = Lzw[k * OC + c];
            float lh = Lhw[k * OC + c];
            az0 += Wz[k] * lz;
            az1 += Wz[OC + k] * lz;
            az2 += Wz[2 * OC + k] * lz;
            az3 += Wz[3 * OC + k] * lz;
            abz += bz[k] * lz;
            ah0 += Wh[k] * lh;
            ah1 += Wh[OC + k] * lh;
            ah2 += Wh[2 * OC + k] * lh;
            ah3 += Wh[3 * OC + k] * lh;
            abh += bh[k] * lh;
        }
        const float sz = LOG2E, sh2 = 2.0f * LOG2E;
        Mz[c] = az0 * sz; Mz[OC + c] = az1 * sz; Mz[2 * OC + c] = az2 * sz; Mz[3 * OC + c] = az3 * sz;
        Mh[c] = ah0 * sh2; Mh[OC + c] = ah1 * sh2; Mh[2 * OC + c] = ah2 * sh2; Mh[3 * OC + c] = ah3 * sh2;
        cz[c] = (abz + Lzb[c]) * sz;
        ch[c] = (abh + Lhb[c]) * sh2;
        if (c == 0) {
            float m = att[0];
            for (int t = 1; t < TP; ++t) m = fmaxf(m, att[t]);
            float sum = 0.0f, e[TP];
            for (int t = 0; t < TP; ++t) { e[t] = expf(att[t] - m); sum += e[t]; }
            for (int t = 0; t < TP; ++t) probs[t] = e[t] / sum;
        }
    } else {
        if (tid < HIDN)
            for (int k = 0; k < OD; ++k) W2T[k * HIDN + tid] = W2[tid * OD + k];
    }
}

// ---- K3: fold full norm into ELL records: r.y = w * dinv[src] * dinv[dst] ----
__global__ __launch_bounds__(256) void norm_kernel(
    const int* __restrict__ cnt, const float* __restrict__ dinv, float2* __restrict__ ell) {
    int idx = blockIdx.x * 256 + threadIdx.x;       // NN*CAP = 1.28M, exact grid
    int n = idx >> 6;                               // CAP = 64
    int slot = idx & (CAP - 1);
    if (slot < cnt[n]) {
        float2 r = ell[idx];
        int s = __float_as_int(r.x);
        ell[idx].y = r.y * dinv[s] * dinv[n];
    }
}

// ---- K4: gather P = A@X (2 threads per (n,t), shfl-pair reduce, no LDS) ----
__global__ __launch_bounds__(256) void gather_kernel(
    const int* __restrict__ cnt, const float* __restrict__ dinv,
    const float2* __restrict__ ell, const float4* __restrict__ XT4,
    const float* __restrict__ x, int useXT, float4* __restrict__ P4) {
    int idx = blockIdx.x * 256 + threadIdx.x;       // 2*NN*TP = 480000, exact grid
    int q = idx & 1;
    int i = idx >> 1;
    int n = i / TP;
    int t = i - n * TP;
    float4 acc = make_float4(0.f, 0.f, 0.f, 0.f);
    if (q == 0) {
        float dn = dinv[n];
        float sw = dn * dn;
        float4 xv = load_xrow(XT4, x, useXT, n, t);
        acc = make_float4(sw * xv.x, sw * xv.y, sw * xv.z, sw * xv.w);
    }
    int cn = cnt[n];
    cn = cn < CAP ? cn : CAP;
    for (int e = q; e < cn; e += 2) {
        float2 r = ell[n * CAP + e];
        float4 xs = load_xrow(XT4, x, useXT, __float_as_int(r.x), t);
        acc.x = fmaf(r.y, xs.x, acc.x);
        acc.y = fmaf(r.y, xs.y, acc.y);
        acc.z = fmaf(r.y, xs.z, acc.z);
        acc.w = fmaf(r.y, xs.w, acc.w);
    }
    acc.x += __shfl_xor(acc.x, 1);
    acc.y += __shfl_xor(acc.y, 1);
    acc.z += __shfl_xor(acc.z, 1);
    acc.w += __shfl_xor(acc.w, 1);
    if (q == 0) P4[i] = acc;
}

// ---- tier B fallback: P = A@X via global atomics ----
__global__ __launch_bounds__(256) void initP_kernel(
    const float* __restrict__ x, const float* __restrict__ dinv, float4* __restrict__ P4) {
    int idx = blockIdx.x * 256 + threadIdx.x;
    if (idx >= NN * TP) return;
    int n = idx / TP;
    int t = idx - n * TP;
    const float* xb = x + n * FT + t;
    float dn = dinv[n], s = dn * dn;
    P4[idx] = make_float4(s * xb[0], s * xb[12], s * xb[24], s * xb[36]);
}

__global__ __launch_bounds__(256) void scatterB_kernel(
    const void* ei, const float* __restrict__ w, const float* __restrict__ dinv,
    const float* __restrict__ x, float* __restrict__ P) {
    int idx = blockIdx.x * 256 + threadIdx.x;
    if (idx >= NE * FT) return;
    int is64 = detect64(ei);
    int e = idx / FT;
    int k = idx - e * FT;
    int src = load_idx(ei, is64, e);
    int dst = load_idx(ei, is64, (long)NE + e);
    float nrm = dinv[src] * w[e] * dinv[dst];
    int t = k >> 2, f = k & 3;
    atomicAdd(&P[dst * FT + k], nrm * x[src * FT + f * TP + t]);
}

// ---- K5: gate accumulation, 8 nodes/block, plain scalar math ----
__global__ __launch_bounds__(256) void gate_kernel(
    const float4* __restrict__ P4,
    const float* __restrict__ Mz, const float* __restrict__ Mh,
    const float* __restrict__ cz, const float* __restrict__ ch,
    const float* __restrict__ probs, float* __restrict__ out) {
    int c = threadIdx.x;
    int nb = blockIdx.x * NG;
    __shared__ float4 shp4[NG * TP];               // 1.5 KB
    if (c < NG * TP) shp4[c] = P4[nb * TP + c];
    float mz0 = Mz[c], mz1 = Mz[OC + c], mz2 = Mz[2 * OC + c], mz3 = Mz[3 * OC + c];
    float mh0 = Mh[c], mh1 = Mh[OC + c], mh2 = Mh[2 * OC + c], mh3 = Mh[3 * OC + c];
    float czc = cz[c], chc = ch[c];
    float pr[TP];
#pragma unroll
    for (int t = 0; t < TP; ++t) pr[t] = probs[t];
    __syncthreads();
    for (int m = 0; m < NG; ++m) {                 // rolled: keep I-cache footprint small
        float hacc = 0.0f;
#pragma unroll
        for (int t = 0; t < TP; ++t) {
            float4 p = shp4[m * TP + t];
            float az = czc, ah = chc;
            az = fmaf(p.x, mz0, az); ah = fmaf(p.x, mh0, ah);
            az = fmaf(p.y, mz1, az); ah = fmaf(p.y, mh1, ah);
            az = fmaf(p.z, mz2, az); ah = fmaf(p.z, mh2, ah);
            az = fmaf(p.w, mz3, az); ah = fmaf(p.w, mh3, ah);
            float ea = __builtin_exp2f(az);        // e^{az}   (az pre-scaled log2e)
            float eb = __builtin_exp2f(ah);        // e^{2ah}  (ah pre-scaled 2log2e)
            // (1-sigmoid(az))*tanh(ah) = (eb-1)/((1+ea)(1+eb))
            float den = (1.0f + ea) * (1.0f + eb);
            float num = pr[t] * (eb - 1.0f);
            hacc = fmaf(num, __builtin_amdgcn_rcpf(den), hacc);
        }
        out[NN * OD + (nb + m) * OC + c] = hacc;   // out_hidden (raw)
    }
}

// ---- K6: output MLP, 16 nodes/block; reads out_hidden back, relu on load ----
__global__ __launch_bounds__(256) void mlp_kernel(
    const float* __restrict__ W1, const float* __restrict__ b1,
    const float* __restrict__ W2T, const float* __restrict__ b2,
    float* __restrict__ out) {
    int c = threadIdx.x;
    int nb = blockIdx.x * NM;
    __shared__ float shh[NM][OC];                  // 16 KB
    __shared__ float shh1[NM][HIDN + 4];           // 8.25 KB
#pragma unroll
    for (int m = 0; m < NM; ++m)
        shh[m][c] = fmaxf(out[NN * OD + (nb + m) * OC + c], 0.0f);
    __syncthreads();

    // layer 1: thread = (half: 8 nodes) x (j: 128); W1 [k][j] coalesced, shh broadcast
    {
        int j = c & (HIDN - 1);
        int m0 = (c >> 7) * 8;
        float s[8];
#pragma unroll
        for (int i = 0; i < 8; ++i) s[i] = 0.0f;
        for (int k4 = 0; k4 < OC / 4; ++k4) {
            int kb = k4 * 4;
            float w0 = W1[(kb + 0) * HIDN + j];
            float w1 = W1[(kb + 1) * HIDN + j];
            float w2 = W1[(kb + 2) * HIDN + j];
            float w3 = W1[(kb + 3) * HIDN + j];
#pragma unroll
            for (int i = 0; i < 8; ++i) {
                float4 h = *(const float4*)&shh[m0 + i][kb];
                s[i] = fmaf(w0, h.x, fmaf(w1, h.y, fmaf(w2, h.z, fmaf(w3, h.w, s[i]))));
            }
        }
        float bb = b1[j];
#pragma unroll
        for (int i = 0; i < 8; ++i)
            shh1[m0 + i][j] = fmaxf(s[i] + bb, 0.0f);
    }
    __syncthreads();

    // layer 2: 192 threads = 16 nodes x 12 outputs
    if (c < NM * OD) {
        int m = c / OD;
        int k = c - m * OD;
        const float4* w2r = (const float4*)&W2T[k * HIDN];
        const float4* hr  = (const float4*)&shh1[m][0];
        float a = b2[k];
        for (int j4 = 0; j4 < HIDN / 4; ++j4) {
            float4 w = w2r[j4];
            float4 h = hr[j4];
            a = fmaf(w.x, h.x, fmaf(w.y, h.y, fmaf(w.z, h.z, fmaf(w.w, h.w, a))));
        }
        out[(nb + m) * OD + k] = a;
    }
}

extern "C" void kernel_launch(void* const* d_in, const int* in_sizes, int n_in,
                              void* d_out, int out_size, void* d_ws, size_t ws_size,
                              hipStream_t stream) {
    const float* x   = (const float*)d_in[0];
    const void*  ei  = d_in[1];
    const float* ea  = (const float*)d_in[2];
    const float* att = (const float*)d_in[3];
    const float* Wz  = (const float*)d_in[4];
    const float* bz  = (const float*)d_in[5];
    // d_in[6], d_in[7] (Wr, br) dead: Hzero*R == 0 in the reference
    const float* Wh  = (const float*)d_in[8];
    const float* bh  = (const float*)d_in[9];
    const float* Lzw = (const float*)d_in[10];
    const float* Lzb = (const float*)d_in[11];
    // d_in[12], d_in[13] (Lrw, Lrb) dead
    const float* Lhw = (const float*)d_in[14];
    const float* Lhb = (const float*)d_in[15];
    const float* W1  = (const float*)d_in[16];
    const float* b1  = (const float*)d_in[17];
    const float* W2  = (const float*)d_in[18];
    const float* b2  = (const float*)d_in[19];

    float* out = (float*)d_out;
    float* ws  = (float*)d_ws;

    int*    cnt   = (int*)(ws + OFF_CNT);
    float*  deg   = ws + OFF_DEG;
    float*  dinv  = ws + OFF_DINV;
    float*  Mz    = ws + OFF_MZ;
    float*  Mh    = ws + OFF_MH;
    float*  cz    = ws + OFF_CZ;
    float*  ch    = ws + OFF_CH;
    float*  probs = ws + OFF_PROBS;
    float*  W2T   = ws + OFF_W2T;
    float2* ell   = (float2*)(ws + OFF_ELL);
    float*  XT    = ws + OFF_XT;

    int useELL = (ws_size >= NEED_ELL) ? 1 : 0;
    int useXT  = (ws_size >= NEED_XT) ? 1 : 0;
    float* P = useELL ? (ws + OFF_P) : (ws + OFF_ELL);   // tier B reuses ELL space

    // zero cnt + deg
    hipMemsetAsync(ws, 0, (size_t)OFF_DINV * sizeof(float), stream);
    build_kernel<<<NB_E + (useXT ? NB_XT : 0), 256, 0, stream>>>(
        ei, ea, x, cnt, deg, ell, (float4*)XT, useELL, useXT);
    prep_kernel<<<NB_DINV + 2, 256, 0, stream>>>(
        deg, dinv, Wz, bz, Wh, bh, Lzw, Lzb, Lhw, Lhb, att, W2,
        Mz, Mh, cz, ch, probs, W2T);
    if (useELL) {
        norm_kernel<<<NN * CAP / 256, 256, 0, stream>>>(cnt, dinv, ell);
        gather_kernel<<<2 * NN * TP / 256, 256, 0, stream>>>(
            cnt, dinv, ell, (const float4*)XT, x, useXT, (float4*)P);
    } else {
        initP_kernel<<<(NN * TP + 255) / 256, 256, 0, stream>>>(x, dinv, (float4*)P);
        scatterB_kernel<<<(NE * FT + 255) / 256, 256, 0, stream>>>(ei, ea, dinv, x, P);
    }
    gate_kernel<<<NN / NG, 256, 0, stream>>>((const float4*)P, Mz, Mh, cz, ch, probs, out);
    mlp_kernel<<<NN / NM, 256, 0, stream>>>(W1, b1, W2T, b2, out);
}

// Round 9
// 169.938 us; speedup vs baseline: 1.0947x; 1.0947x over previous
//
#include <hip/hip_runtime.h>
#include <math.h>

#define NN 20000
#define NE 320000
#define TP 12
#define OC 256
#define HIDN 128
#define OD 12
#define FT 48            // FIN*TP
#define CAP 64           // ELL row capacity (deg ~Poisson(16); P(>64) negligible)
#define NPB 16           // nodes per block, fused gate+mlp kernel
#define LOG2E 1.44269504088896340736f

#define NB_E    ((NE + 255) / 256)         // 1250
#define NB_XT   ((NN * TP + 255) / 256)    // 938
#define NB_DINV ((NN + 255) / 256)         // 79

// ---- workspace layout (float indices) ----
#define OFF_CNT    0                        // int[NN]
#define OFF_DEG    (OFF_CNT + NN)           // float[NN]
#define OFF_DINV   (OFF_DEG + NN)           // float[NN]
#define OFF_MZ     (OFF_DINV + NN)          // float[4*OC], pre-scaled log2e
#define OFF_MH     (OFF_MZ + 4*OC)          // float[4*OC], pre-scaled 2*log2e
#define OFF_CZ     (OFF_MH + 4*OC)
#define OFF_CH     (OFF_CZ + OC)
#define OFF_PROBS  (OFF_CH + OC)
#define OFF_W2T    (OFF_PROBS + 16)         // [k][j] 12x128
#define OFF_ELL    (OFF_W2T + HIDN*OD)      // float2[NN*CAP] {src,w} | tierB: P
#define OFF_P      (OFF_ELL + 2*NN*CAP)     // float4[NN*TP]
#define OFF_XT     (OFF_P + NN*FT)          // float4[NN*TP], scaled to dinv[n]*x[n] by prep
#define NEED_ELL   ((size_t)(OFF_XT) * 4)              // ELL + P, no XT
#define NEED_XT    ((size_t)(OFF_XT + NN*FT) * 4)      // everything

// ---- per-wave int64/int32 detection ----
__device__ __forceinline__ int detect64(const void* ei) {
    const unsigned long long* p = (const unsigned long long*)ei;
    unsigned long long v = p[threadIdx.x & 63];
    return (__ballot(v < (unsigned long long)NN) == ~0ull) ? 1 : 0;
}

__device__ __forceinline__ int load_idx(const void* ei, int is64, long off) {
    return is64 ? (int)((const long long*)ei)[off] : ((const int*)ei)[off];
}

// ---- K1: single-pass ELL build (deg + cnt + records); extra blocks: x -> XT (raw) ----
__global__ __launch_bounds__(256) void build_kernel(
    const void* ei, const float* __restrict__ w, const float* __restrict__ x,
    int* __restrict__ cnt, float* __restrict__ deg, float2* __restrict__ ell,
    float4* __restrict__ XT4, int useELL, int useXT) {
    int bid = blockIdx.x;
    if (bid < NB_E) {
        int is64 = detect64(ei);
        int e = bid * 256 + threadIdx.x;
        if (e < NE) {
            int src = load_idx(ei, is64, e);
            int dst = load_idx(ei, is64, (long)NE + e);
            float we = w[e];
            atomicAdd(&deg[dst], we);
            if (useELL) {
                int slot = atomicAdd(&cnt[dst], 1);
                if (slot < CAP)
                    ell[dst * CAP + slot] = make_float2(__int_as_float(src), we);
            }
        }
    } else if (useXT) {
        int idx = (bid - NB_E) * 256 + threadIdx.x;
        if (idx < NN * TP) {
            int n = idx / TP;
            int t = idx - n * TP;
            const float* xb = x + n * FT + t;
            XT4[idx] = make_float4(xb[0], xb[12], xb[24], xb[36]);
        }
    }
}

// ---- K2: 0..78 dinv; 79 weight fold + probs; 80 W2T; 81+ scale XT by dinv[n] ----
__global__ __launch_bounds__(256) void prep_kernel(
    const float* __restrict__ deg, float* __restrict__ dinv,
    const float* __restrict__ Wz, const float* __restrict__ bz,
    const float* __restrict__ Wh, const float* __restrict__ bh,
    const float* __restrict__ Lzw, const float* __restrict__ Lzb,
    const float* __restrict__ Lhw, const float* __restrict__ Lhb,
    const float* __restrict__ att, const float* __restrict__ W2,
    float* __restrict__ Mz, float* __restrict__ Mh,
    float* __restrict__ cz, float* __restrict__ ch,
    float* __restrict__ probs, float* __restrict__ W2T, float4* __restrict__ XT4) {
    int bid = blockIdx.x;
    int tid = threadIdx.x;
    if (bid < NB_DINV) {
        int n = bid * 256 + tid;
        if (n < NN) dinv[n] = 1.0f / sqrtf(deg[n] + 1.0f);   // + self-loop weight
    } else if (bid == NB_DINV) {
        int c = tid;
        float az0 = 0, az1 = 0, az2 = 0, az3 = 0, abz = 0;
        float ah0 = 0, ah1 = 0, ah2 = 0, ah3 = 0, abh = 0;
        for (int k = 0; k < OC; ++k) {
            float lz = Lzw[k * OC + c];
            float lh = Lhw[k * OC + c];
            az0 += Wz[k] * lz;
            az1 += Wz[OC + k] * lz;
            az2 += Wz[2 * OC + k] * lz;
            az3 += Wz[3 * OC + k] * lz;
            abz += bz[k] * lz;
            ah0 += Wh[k] * lh;
            ah1 += Wh[OC + k] * lh;
            ah2 += Wh[2 * OC + k] * lh;
            ah3 += Wh[3 * OC + k] * lh;
            abh += bh[k] * lh;
        }
        const float sz = LOG2E, sh2 = 2.0f * LOG2E;
        Mz[c] = az0 * sz; Mz[OC + c] = az1 * sz; Mz[2 * OC + c] = az2 * sz; Mz[3 * OC + c] = az3 * sz;
        Mh[c] = ah0 * sh2; Mh[OC + c] = ah1 * sh2; Mh[2 * OC + c] = ah2 * sh2; Mh[3 * OC + c] = ah3 * sh2;
        cz[c] = (abz + Lzb[c]) * sz;
        ch[c] = (abh + Lhb[c]) * sh2;
        if (c == 0) {
            float m = att[0];
            for (int t = 1; t < TP; ++t) m = fmaxf(m, att[t]);
            float sum = 0.0f, e[TP];
            for (int t = 0; t < TP; ++t) { e[t] = expf(att[t] - m); sum += e[t]; }
            for (int t = 0; t < TP; ++t) probs[t] = e[t] / sum;
        }
    } else if (bid == NB_DINV + 1) {
        if (tid < HIDN)
            for (int k = 0; k < OD; ++k) W2T[k * HIDN + tid] = W2[tid * OD + k];
    } else {
        // XTs[n] = dinv[n] * x[n] (recompute dn locally: no cross-block dependence)
        int idx = (bid - (NB_DINV + 2)) * 256 + tid;
        if (idx < NN * TP) {
            int n = idx / TP;
            float dn = 1.0f / sqrtf(deg[n] + 1.0f);
            float4 v = XT4[idx];
            XT4[idx] = make_float4(dn * v.x, dn * v.y, dn * v.z, dn * v.w);
        }
    }
}

// ---- K3: gather P = dinv[n]*(XTs[n] + sum w_e*XTs[src]) (2 threads per (n,t)) ----
__global__ __launch_bounds__(256) void gather_kernel(
    const int* __restrict__ cnt, const float* __restrict__ dinv,
    const float2* __restrict__ ell, const float4* __restrict__ XT4,
    const float* __restrict__ x, int useXT, float4* __restrict__ P4) {
    int idx = blockIdx.x * 256 + threadIdx.x;       // 2*NN*TP = 480000, exact grid
    int q = idx & 1;
    int i = idx >> 1;
    int n = i / TP;
    int t = i - n * TP;
    float4 acc = make_float4(0.f, 0.f, 0.f, 0.f);
    if (q == 0) {
        if (useXT) acc = XT4[n * TP + t];           // already dinv[n]*x[n]
        else {
            const float* xb = x + n * FT + t;
            float dn = dinv[n];
            acc = make_float4(dn * xb[0], dn * xb[12], dn * xb[24], dn * xb[36]);
        }
    }
    int cn = cnt[n];
    cn = cn < CAP ? cn : CAP;
    for (int e = q; e < cn; e += 2) {
        float2 r = ell[n * CAP + e];
        int s = __float_as_int(r.x);
        float4 xs;
        float wv = r.y;
        if (useXT) xs = XT4[s * TP + t];
        else {
            const float* xb = x + s * FT + t;
            xs = make_float4(xb[0], xb[12], xb[24], xb[36]);
            wv *= dinv[s];
        }
        acc.x = fmaf(wv, xs.x, acc.x);
        acc.y = fmaf(wv, xs.y, acc.y);
        acc.z = fmaf(wv, xs.z, acc.z);
        acc.w = fmaf(wv, xs.w, acc.w);
    }
    acc.x += __shfl_xor(acc.x, 1);
    acc.y += __shfl_xor(acc.y, 1);
    acc.z += __shfl_xor(acc.z, 1);
    acc.w += __shfl_xor(acc.w, 1);
    if (q == 0) {
        float dn = dinv[n];
        P4[i] = make_float4(dn * acc.x, dn * acc.y, dn * acc.z, dn * acc.w);
    }
}

// ---- tier B fallback: P = A@X via global atomics ----
__global__ __launch_bounds__(256) void initP_kernel(
    const float* __restrict__ x, const float* __restrict__ dinv, float4* __restrict__ P4) {
    int idx = blockIdx.x * 256 + threadIdx.x;
    if (idx >= NN * TP) return;
    int n = idx / TP;
    int t = idx - n * TP;
    const float* xb = x + n * FT + t;
    float dn = dinv[n], s = dn * dn;
    P4[idx] = make_float4(s * xb[0], s * xb[12], s * xb[24], s * xb[36]);
}

__global__ __launch_bounds__(256) void scatterB_kernel(
    const void* ei, const float* __restrict__ w, const float* __restrict__ dinv,
    const float* __restrict__ x, float* __restrict__ P) {
    int idx = blockIdx.x * 256 + threadIdx.x;
    if (idx >= NE * FT) return;
    int is64 = detect64(ei);
    int e = idx / FT;
    int k = idx - e * FT;
    int src = load_idx(ei, is64, e);
    int dst = load_idx(ei, is64, (long)NE + e);
    float nrm = dinv[src] * w[e] * dinv[dst];
    int t = k >> 2, f = k & 3;
    atomicAdd(&P[dst * FT + k], nrm * x[src * FT + f * TP + t]);
}

// ---- K4: fused gate + MLP, 512 threads, 16 nodes/block, LDS handoff ----
__global__ __launch_bounds__(512, 8) void fused_kernel(
    const float4* __restrict__ P4,
    const float* __restrict__ Mz, const float* __restrict__ Mh,
    const float* __restrict__ cz, const float* __restrict__ chv,
    const float* __restrict__ probs,
    const float* __restrict__ W1, const float* __restrict__ b1,
    const float* __restrict__ W2T, const float* __restrict__ b2,
    float* __restrict__ out) {
    int c = threadIdx.x;
    int ch = c & (OC - 1);                         // channel 0..255
    int half = c >> 8;                             // 0..1
    int nb = blockIdx.x * NPB;
    __shared__ float4 shp4[NPB * TP];              // 3 KB
    __shared__ float shh[NPB][OC];                 // 16 KB
    __shared__ float shh1[NPB][HIDN + 4];          // 8.25 KB

    if (c < NPB * TP) shp4[c] = P4[nb * TP + c];
    float mz0 = Mz[ch], mz1 = Mz[OC + ch], mz2 = Mz[2 * OC + ch], mz3 = Mz[3 * OC + ch];
    float mh0 = Mh[ch], mh1 = Mh[OC + ch], mh2 = Mh[2 * OC + ch], mh3 = Mh[3 * OC + ch];
    float czc = cz[ch], chc = chv[ch];
    float pr[TP];
#pragma unroll
    for (int t = 0; t < TP; ++t) pr[t] = probs[t];
    __syncthreads();

    // ---- gate: each thread does 8 nodes x 12 t; 2 partial chains for ILP ----
    int m0 = half * 8;
#pragma unroll 2
    for (int mm = 0; mm < 8; ++mm) {
        int m = m0 + mm;
        float ha = 0.0f, hb = 0.0f;
#pragma unroll
        for (int t = 0; t < TP; t += 2) {
#pragma unroll
            for (int u = 0; u < 2; ++u) {
                float4 p = shp4[m * TP + t + u];
                float az = czc, ah = chc;
                az = fmaf(p.x, mz0, az); ah = fmaf(p.x, mh0, ah);
                az = fmaf(p.y, mz1, az); ah = fmaf(p.y, mh1, ah);
                az = fmaf(p.z, mz2, az); ah = fmaf(p.z, mh2, ah);
                az = fmaf(p.w, mz3, az); ah = fmaf(p.w, mh3, ah);
                float ea = __builtin_exp2f(az);    // e^{az}   (pre-scaled log2e)
                float eb = __builtin_exp2f(ah);    // e^{2ah}  (pre-scaled 2log2e)
                // (1-sigmoid(az))*tanh(ah) = (eb-1)/((1+ea)(1+eb))
                float den = (1.0f + ea) * (1.0f + eb);
                float num = pr[t + u] * (eb - 1.0f);
                float v = num * __builtin_amdgcn_rcpf(den);
                if (u == 0) ha += v; else hb += v;
            }
        }
        float hacc = ha + hb;
        out[NN * OD + (nb + m) * OC + ch] = hacc;  // out_hidden (raw)
        shh[m][ch] = fmaxf(hacc, 0.0f);
    }
    __syncthreads();

    // ---- layer 1: thread = (quarter: 4 nodes) x (j: 128); W1 coalesced, shh broadcast ----
    {
        int j = c & (HIDN - 1);
        int mq = (c >> 7) * 4;
        float s0 = 0, s1 = 0, s2 = 0, s3 = 0;
        for (int k4 = 0; k4 < OC / 4; ++k4) {
            int kb = k4 * 4;
            float w0 = W1[(kb + 0) * HIDN + j];
            float w1 = W1[(kb + 1) * HIDN + j];
            float w2 = W1[(kb + 2) * HIDN + j];
            float w3 = W1[(kb + 3) * HIDN + j];
            float4 h0 = *(const float4*)&shh[mq + 0][kb];
            float4 h1 = *(const float4*)&shh[mq + 1][kb];
            float4 h2 = *(const float4*)&shh[mq + 2][kb];
            float4 h3 = *(const float4*)&shh[mq + 3][kb];
            s0 = fmaf(w0, h0.x, fmaf(w1, h0.y, fmaf(w2, h0.z, fmaf(w3, h0.w, s0))));
            s1 = fmaf(w0, h1.x, fmaf(w1, h1.y, fmaf(w2, h1.z, fmaf(w3, h1.w, s1))));
            s2 = fmaf(w0, h2.x, fmaf(w1, h2.y, fmaf(w2, h2.z, fmaf(w3, h2.w, s2))));
            s3 = fmaf(w0, h3.x, fmaf(w1, h3.y, fmaf(w2, h3.z, fmaf(w3, h3.w, s3))));
        }
        float bb = b1[j];
        shh1[mq + 0][j] = fmaxf(s0 + bb, 0.0f);
        shh1[mq + 1][j] = fmaxf(s1 + bb, 0.0f);
        shh1[mq + 2][j] = fmaxf(s2 + bb, 0.0f);
        shh1[mq + 3][j] = fmaxf(s3 + bb, 0.0f);
    }
    __syncthreads();

    // ---- layer 2: 192 threads = 16 nodes x 12 outputs ----
    if (c < NPB * OD) {
        int m = c / OD;
        int k = c - m * OD;
        const float4* w2r = (const float4*)&W2T[k * HIDN];
        const float4* hr  = (const float4*)&shh1[m][0];
        float a = b2[k];
        for (int j4 = 0; j4 < HIDN / 4; ++j4) {
            float4 w = w2r[j4];
            float4 h = hr[j4];
            a = fmaf(w.x, h.x, fmaf(w.y, h.y, fmaf(w.z, h.z, fmaf(w.w, h.w, a))));
        }
        out[(nb + m) * OD + k] = a;
    }
}

extern "C" void kernel_launch(void* const* d_in, const int* in_sizes, int n_in,
                              void* d_out, int out_size, void* d_ws, size_t ws_size,
                              hipStream_t stream) {
    const float* x   = (const float*)d_in[0];
    const void*  ei  = d_in[1];
    const float* ea  = (const float*)d_in[2];
    const float* att = (const float*)d_in[3];
    const float* Wz  = (const float*)d_in[4];
    const float* bz  = (const float*)d_in[5];
    // d_in[6], d_in[7] (Wr, br) dead: Hzero*R == 0 in the reference
    const float* Wh  = (const float*)d_in[8];
    const float* bh  = (const float*)d_in[9];
    const float* Lzw = (const float*)d_in[10];
    const float* Lzb = (const float*)d_in[11];
    // d_in[12], d_in[13] (Lrw, Lrb) dead
    const float* Lhw = (const float*)d_in[14];
    const float* Lhb = (const float*)d_in[15];
    const float* W1  = (const float*)d_in[16];
    const float* b1  = (const float*)d_in[17];
    const float* W2  = (const float*)d_in[18];
    const float* b2  = (const float*)d_in[19];

    float* out = (float*)d_out;
    float* ws  = (float*)d_ws;

    int*    cnt   = (int*)(ws + OFF_CNT);
    float*  deg   = ws + OFF_DEG;
    float*  dinv  = ws + OFF_DINV;
    float*  Mz    = ws + OFF_MZ;
    float*  Mh    = ws + OFF_MH;
    float*  cz    = ws + OFF_CZ;
    float*  ch    = ws + OFF_CH;
    float*  probs = ws + OFF_PROBS;
    float*  W2T   = ws + OFF_W2T;
    float2* ell   = (float2*)(ws + OFF_ELL);
    float*  XT    = ws + OFF_XT;

    int useELL = (ws_size >= NEED_ELL) ? 1 : 0;
    int useXT  = (ws_size >= NEED_XT) ? 1 : 0;
    float* P = useELL ? (ws + OFF_P) : (ws + OFF_ELL);   // tier B reuses ELL space

    // zero cnt + deg
    hipMemsetAsync(ws, 0, (size_t)OFF_DINV * sizeof(float), stream);
    build_kernel<<<NB_E + (useXT ? NB_XT : 0), 256, 0, stream>>>(
        ei, ea, x, cnt, deg, ell, (float4*)XT, useELL, useXT);
    prep_kernel<<<NB_DINV + 2 + (useXT ? NB_XT : 0), 256, 0, stream>>>(
        deg, dinv, Wz, bz, Wh, bh, Lzw, Lzb, Lhw, Lhb, att, W2,
        Mz, Mh, cz, ch, probs, W2T, (float4*)XT);
    if (useELL) {
        gather_kernel<<<2 * NN * TP / 256, 256, 0, stream>>>(
            cnt, dinv, ell, (const float4*)XT, x, useXT, (float4*)P);
    } else {
        initP_kernel<<<(NN * TP + 255) / 256, 256, 0, stream>>>(x, dinv, (float4*)P);
        scatterB_kernel<<<(NE * FT + 255) / 256, 256, 0, stream>>>(ei, ea, dinv, x, P);
    }
    fused_kernel<<<NN / NPB, 512, 0, stream>>>((const float4*)P, Mz, Mh, cz, ch, probs,
                                               W1, b1, W2T, b2, out);
}

// Round 10
// 164.577 us; speedup vs baseline: 1.1304x; 1.0326x over previous
//
#include <hip/hip_runtime.h>
#include <math.h>

#define NN 20000
#define NE 320000
#define TP 12
#define OC 256
#define HIDN 128
#define OD 12
#define FT 48            // FIN*TP
#define CAP 64           // ELL row capacity (deg ~Poisson(16); P(>64) negligible)
#define NPB 16           // nodes per block, fused gate+mlp kernel
#define LOG2E 1.44269504088896340736f

#define NB_E    ((NE + 255) / 256)         // 1250
#define NB_XT   ((NN * TP + 255) / 256)    // 938
#define NB_DINV ((NN + 255) / 256)         // 79

// ---- workspace layout (float indices) ----
#define OFF_CNT    0                        // int[NN]
#define OFF_DEG    (OFF_CNT + NN)           // float[NN]
#define OFF_DINV   (OFF_DEG + NN)           // float[NN]
#define OFF_MZ     (OFF_DINV + NN)          // float[4*OC], pre-scaled log2e
#define OFF_MH     (OFF_MZ + 4*OC)          // float[4*OC], pre-scaled 2*log2e
#define OFF_CZ     (OFF_MH + 4*OC)
#define OFF_CH     (OFF_CZ + OC)
#define OFF_PROBS  (OFF_CH + OC)
#define OFF_W2T    (OFF_PROBS + 16)         // [k][j] 12x128
#define OFF_ELL    (OFF_W2T + HIDN*OD)      // float2[NN*CAP] {src,w} | tierB: P
#define OFF_P      (OFF_ELL + 2*NN*CAP)     // float4[NN*TP]
#define OFF_XT     (OFF_P + NN*FT)          // float4[NN*TP], scaled to dinv[n]*x[n] by prep
#define NEED_ELL   ((size_t)(OFF_XT) * 4)              // ELL + P, no XT
#define NEED_XT    ((size_t)(OFF_XT + NN*FT) * 4)      // everything

// ---- per-wave int64/int32 detection ----
__device__ __forceinline__ int detect64(const void* ei) {
    const unsigned long long* p = (const unsigned long long*)ei;
    unsigned long long v = p[threadIdx.x & 63];
    return (__ballot(v < (unsigned long long)NN) == ~0ull) ? 1 : 0;
}

__device__ __forceinline__ int load_idx(const void* ei, int is64, long off) {
    return is64 ? (int)((const long long*)ei)[off] : ((const int*)ei)[off];
}

// ---- K1: single-pass ELL build (deg + cnt + records); extra blocks: x -> XT (raw) ----
__global__ __launch_bounds__(256) void build_kernel(
    const void* ei, const float* __restrict__ w, const float* __restrict__ x,
    int* __restrict__ cnt, float* __restrict__ deg, float2* __restrict__ ell,
    float4* __restrict__ XT4, int useELL, int useXT) {
    int bid = blockIdx.x;
    if (bid < NB_E) {
        int is64 = detect64(ei);
        int e = bid * 256 + threadIdx.x;
        if (e < NE) {
            int src = load_idx(ei, is64, e);
            int dst = load_idx(ei, is64, (long)NE + e);
            float we = w[e];
            atomicAdd(&deg[dst], we);
            if (useELL) {
                int slot = atomicAdd(&cnt[dst], 1);
                if (slot < CAP)
                    ell[dst * CAP + slot] = make_float2(__int_as_float(src), we);
            }
        }
    } else if (useXT) {
        int idx = (bid - NB_E) * 256 + threadIdx.x;
        if (idx < NN * TP) {
            int n = idx / TP;
            int t = idx - n * TP;
            const float* xb = x + n * FT + t;
            XT4[idx] = make_float4(xb[0], xb[12], xb[24], xb[36]);
        }
    }
}

// ---- K2: 0..78 dinv; 79 weight fold + probs; 80 W2T; 81+ scale XT by dinv[n] ----
__global__ __launch_bounds__(256) void prep_kernel(
    const float* __restrict__ deg, float* __restrict__ dinv,
    const float* __restrict__ Wz, const float* __restrict__ bz,
    const float* __restrict__ Wh, const float* __restrict__ bh,
    const float* __restrict__ Lzw, const float* __restrict__ Lzb,
    const float* __restrict__ Lhw, const float* __restrict__ Lhb,
    const float* __restrict__ att, const float* __restrict__ W2,
    float* __restrict__ Mz, float* __restrict__ Mh,
    float* __restrict__ cz, float* __restrict__ ch,
    float* __restrict__ probs, float* __restrict__ W2T, float4* __restrict__ XT4) {
    int bid = blockIdx.x;
    int tid = threadIdx.x;
    if (bid < NB_DINV) {
        int n = bid * 256 + tid;
        if (n < NN) dinv[n] = 1.0f / sqrtf(deg[n] + 1.0f);   // + self-loop weight
    } else if (bid == NB_DINV) {
        int c = tid;
        float az0 = 0, az1 = 0, az2 = 0, az3 = 0, abz = 0;
        float ah0 = 0, ah1 = 0, ah2 = 0, ah3 = 0, abh = 0;
        for (int k = 0; k < OC; ++k) {
            float lz = Lzw[k * OC + c];
            float lh = Lhw[k * OC + c];
            az0 += Wz[k] * lz;
            az1 += Wz[OC + k] * lz;
            az2 += Wz[2 * OC + k] * lz;
            az3 += Wz[3 * OC + k] * lz;
            abz += bz[k] * lz;
            ah0 += Wh[k] * lh;
            ah1 += Wh[OC + k] * lh;
            ah2 += Wh[2 * OC + k] * lh;
            ah3 += Wh[3 * OC + k] * lh;
            abh += bh[k] * lh;
        }
        const float sz = LOG2E, sh2 = 2.0f * LOG2E;
        Mz[c] = az0 * sz; Mz[OC + c] = az1 * sz; Mz[2 * OC + c] = az2 * sz; Mz[3 * OC + c] = az3 * sz;
        Mh[c] = ah0 * sh2; Mh[OC + c] = ah1 * sh2; Mh[2 * OC + c] = ah2 * sh2; Mh[3 * OC + c] = ah3 * sh2;
        cz[c] = (abz + Lzb[c]) * sz;
        ch[c] = (abh + Lhb[c]) * sh2;
        if (c == 0) {
            float m = att[0];
            for (int t = 1; t < TP; ++t) m = fmaxf(m, att[t]);
            float sum = 0.0f, e[TP];
            for (int t = 0; t < TP; ++t) { e[t] = expf(att[t] - m); sum += e[t]; }
            for (int t = 0; t < TP; ++t) probs[t] = e[t] / sum;
        }
    } else if (bid == NB_DINV + 1) {
        if (tid < HIDN)
            for (int k = 0; k < OD; ++k) W2T[k * HIDN + tid] = W2[tid * OD + k];
    } else {
        // XTs[n] = dinv[n] * x[n] (recompute dn locally: no cross-block dependence)
        int idx = (bid - (NB_DINV + 2)) * 256 + tid;
        if (idx < NN * TP) {
            int n = idx / TP;
            float dn = 1.0f / sqrtf(deg[n] + 1.0f);
            float4 v = XT4[idx];
            XT4[idx] = make_float4(dn * v.x, dn * v.y, dn * v.z, dn * v.w);
        }
    }
}

// ---- K3: gather P = dinv[n]*(XTs[n] + sum w_e*XTs[src]) (2 threads per (n,t)) ----
__global__ __launch_bounds__(256) void gather_kernel(
    const int* __restrict__ cnt, const float* __restrict__ dinv,
    const float2* __restrict__ ell, const float4* __restrict__ XT4,
    const float* __restrict__ x, int useXT, float4* __restrict__ P4) {
    int idx = blockIdx.x * 256 + threadIdx.x;       // 2*NN*TP = 480000, exact grid
    int q = idx & 1;
    int i = idx >> 1;
    int n = i / TP;
    int t = i - n * TP;
    float4 acc = make_float4(0.f, 0.f, 0.f, 0.f);
    if (q == 0) {
        if (useXT) acc = XT4[n * TP + t];           // already dinv[n]*x[n]
        else {
            const float* xb = x + n * FT + t;
            float dn = dinv[n];
            acc = make_float4(dn * xb[0], dn * xb[12], dn * xb[24], dn * xb[36]);
        }
    }
    int cn = cnt[n];
    cn = cn < CAP ? cn : CAP;
    for (int e = q; e < cn; e += 2) {
        float2 r = ell[n * CAP + e];
        int s = __float_as_int(r.x);
        float4 xs;
        float wv = r.y;
        if (useXT) xs = XT4[s * TP + t];
        else {
            const float* xb = x + s * FT + t;
            xs = make_float4(xb[0], xb[12], xb[24], xb[36]);
            wv *= dinv[s];
        }
        acc.x = fmaf(wv, xs.x, acc.x);
        acc.y = fmaf(wv, xs.y, acc.y);
        acc.z = fmaf(wv, xs.z, acc.z);
        acc.w = fmaf(wv, xs.w, acc.w);
    }
    acc.x += __shfl_xor(acc.x, 1);
    acc.y += __shfl_xor(acc.y, 1);
    acc.z += __shfl_xor(acc.z, 1);
    acc.w += __shfl_xor(acc.w, 1);
    if (q == 0) {
        float dn = dinv[n];
        P4[i] = make_float4(dn * acc.x, dn * acc.y, dn * acc.z, dn * acc.w);
    }
}

// ---- tier B fallback: P = A@X via global atomics ----
__global__ __launch_bounds__(256) void initP_kernel(
    const float* __restrict__ x, const float* __restrict__ dinv, float4* __restrict__ P4) {
    int idx = blockIdx.x * 256 + threadIdx.x;
    if (idx >= NN * TP) return;
    int n = idx / TP;
    int t = idx - n * TP;
    const float* xb = x + n * FT + t;
    float dn = dinv[n], s = dn * dn;
    P4[idx] = make_float4(s * xb[0], s * xb[12], s * xb[24], s * xb[36]);
}

__global__ __launch_bounds__(256) void scatterB_kernel(
    const void* ei, const float* __restrict__ w, const float* __restrict__ dinv,
    const float* __restrict__ x, float* __restrict__ P) {
    int idx = blockIdx.x * 256 + threadIdx.x;
    if (idx >= NE * FT) return;
    int is64 = detect64(ei);
    int e = idx / FT;
    int k = idx - e * FT;
    int src = load_idx(ei, is64, e);
    int dst = load_idx(ei, is64, (long)NE + e);
    float nrm = dinv[src] * w[e] * dinv[dst];
    int t = k >> 2, f = k & 3;
    atomicAdd(&P[dst * FT + k], nrm * x[src * FT + f * TP + t]);
}

// ---- K4: fused gate + MLP, 512 threads, 16 nodes/block, LDS handoff ----
// launch_bounds(512,4): <=128 VGPR so 4-6 independent exp/rcp chains stay in flight
__global__ __launch_bounds__(512, 4) void fused_kernel(
    const float4* __restrict__ P4,
    const float* __restrict__ Mz, const float* __restrict__ Mh,
    const float* __restrict__ cz, const float* __restrict__ chv,
    const float* __restrict__ probs,
    const float* __restrict__ W1, const float* __restrict__ b1,
    const float* __restrict__ W2T, const float* __restrict__ b2,
    float* __restrict__ out) {
    int c = threadIdx.x;
    int ch = c & (OC - 1);                         // channel 0..255
    int half = c >> 8;                             // 0..1
    int nb = blockIdx.x * NPB;
    __shared__ float4 shp4[NPB * TP];              // 3 KB
    __shared__ float shh[NPB][OC];                 // 16 KB
    __shared__ float shh1[NPB][HIDN + 4];          // 8.25 KB

    if (c < NPB * TP) shp4[c] = P4[nb * TP + c];
    float mz0 = Mz[ch], mz1 = Mz[OC + ch], mz2 = Mz[2 * OC + ch], mz3 = Mz[3 * OC + ch];
    float mh0 = Mh[ch], mh1 = Mh[OC + ch], mh2 = Mh[2 * OC + ch], mh3 = Mh[3 * OC + ch];
    float czc = cz[ch], chc = chv[ch];
    float pr[TP];
#pragma unroll
    for (int t = 0; t < TP; ++t) pr[t] = probs[t];
    __syncthreads();

    // ---- gate: 2 nodes at a time, t fully unrolled -> many independent chains ----
    int m0 = half * 8;
#pragma unroll
    for (int mm = 0; mm < 8; mm += 2) {
        int ma = m0 + mm;
        int mb = ma + 1;
        float acc_a = 0.0f, acc_b = 0.0f;
#pragma unroll
        for (int t = 0; t < TP; ++t) {
            float4 pa = shp4[ma * TP + t];
            float4 pb = shp4[mb * TP + t];
            float aza = czc, aha = chc, azb = czc, ahb = chc;
            aza = fmaf(pa.x, mz0, aza); aha = fmaf(pa.x, mh0, aha);
            azb = fmaf(pb.x, mz0, azb); ahb = fmaf(pb.x, mh0, ahb);
            aza = fmaf(pa.y, mz1, aza); aha = fmaf(pa.y, mh1, aha);
            azb = fmaf(pb.y, mz1, azb); ahb = fmaf(pb.y, mh1, ahb);
            aza = fmaf(pa.z, mz2, aza); aha = fmaf(pa.z, mh2, aha);
            azb = fmaf(pb.z, mz2, azb); ahb = fmaf(pb.z, mh2, ahb);
            aza = fmaf(pa.w, mz3, aza); aha = fmaf(pa.w, mh3, aha);
            azb = fmaf(pb.w, mz3, azb); ahb = fmaf(pb.w, mh3, ahb);
            float eaa = __builtin_exp2f(aza);      // e^{az}   (pre-scaled log2e)
            float eba = __builtin_exp2f(aha);      // e^{2ah}  (pre-scaled 2log2e)
            float eab = __builtin_exp2f(azb);
            float ebb = __builtin_exp2f(ahb);
            // (1-sigmoid(az))*tanh(ah) = (eb-1)/((1+ea)(1+eb))
            float dena = (1.0f + eaa) * (1.0f + eba);
            float denb = (1.0f + eab) * (1.0f + ebb);
            float numa = pr[t] * (eba - 1.0f);
            float numb = pr[t] * (ebb - 1.0f);
            acc_a = fmaf(numa, __builtin_amdgcn_rcpf(dena), acc_a);
            acc_b = fmaf(numb, __builtin_amdgcn_rcpf(denb), acc_b);
        }
        out[NN * OD + (nb + ma) * OC + ch] = acc_a;    // out_hidden (raw)
        out[NN * OD + (nb + mb) * OC + ch] = acc_b;
        shh[ma][ch] = fmaxf(acc_a, 0.0f);
        shh[mb][ch] = fmaxf(acc_b, 0.0f);
    }
    __syncthreads();

    // ---- layer 1: thread = (quarter: 4 nodes) x (j: 128); W1 coalesced, shh broadcast ----
    {
        int j = c & (HIDN - 1);
        int mq = (c >> 7) * 4;
        float s0 = 0, s1 = 0, s2 = 0, s3 = 0;
        for (int k4 = 0; k4 < OC / 4; ++k4) {
            int kb = k4 * 4;
            float w0 = W1[(kb + 0) * HIDN + j];
            float w1 = W1[(kb + 1) * HIDN + j];
            float w2 = W1[(kb + 2) * HIDN + j];
            float w3 = W1[(kb + 3) * HIDN + j];
            float4 h0 = *(const float4*)&shh[mq + 0][kb];
            float4 h1 = *(const float4*)&shh[mq + 1][kb];
            float4 h2 = *(const float4*)&shh[mq + 2][kb];
            float4 h3 = *(const float4*)&shh[mq + 3][kb];
            s0 = fmaf(w0, h0.x, fmaf(w1, h0.y, fmaf(w2, h0.z, fmaf(w3, h0.w, s0))));
            s1 = fmaf(w0, h1.x, fmaf(w1, h1.y, fmaf(w2, h1.z, fmaf(w3, h1.w, s1))));
            s2 = fmaf(w0, h2.x, fmaf(w1, h2.y, fmaf(w2, h2.z, fmaf(w3, h2.w, s2))));
            s3 = fmaf(w0, h3.x, fmaf(w1, h3.y, fmaf(w2, h3.z, fmaf(w3, h3.w, s3))));
        }
        float bb = b1[j];
        shh1[mq + 0][j] = fmaxf(s0 + bb, 0.0f);
        shh1[mq + 1][j] = fmaxf(s1 + bb, 0.0f);
        shh1[mq + 2][j] = fmaxf(s2 + bb, 0.0f);
        shh1[mq + 3][j] = fmaxf(s3 + bb, 0.0f);
    }
    __syncthreads();

    // ---- layer 2: 192 threads = 16 nodes x 12 outputs ----
    if (c < NPB * OD) {
        int m = c / OD;
        int k = c - m * OD;
        const float4* w2r = (const float4*)&W2T[k * HIDN];
        const float4* hr  = (const float4*)&shh1[m][0];
        float a = b2[k];
        for (int j4 = 0; j4 < HIDN / 4; ++j4) {
            float4 w = w2r[j4];
            float4 h = hr[j4];
            a = fmaf(w.x, h.x, fmaf(w.y, h.y, fmaf(w.z, h.z, fmaf(w.w, h.w, a))));
        }
        out[(nb + m) * OD + k] = a;
    }
}

extern "C" void kernel_launch(void* const* d_in, const int* in_sizes, int n_in,
                              void* d_out, int out_size, void* d_ws, size_t ws_size,
                              hipStream_t stream) {
    const float* x   = (const float*)d_in[0];
    const void*  ei  = d_in[1];
    const float* ea  = (const float*)d_in[2];
    const float* att = (const float*)d_in[3];
    const float* Wz  = (const float*)d_in[4];
    const float* bz  = (const float*)d_in[5];
    // d_in[6], d_in[7] (Wr, br) dead: Hzero*R == 0 in the reference
    const float* Wh  = (const float*)d_in[8];
    const float* bh  = (const float*)d_in[9];
    const float* Lzw = (const float*)d_in[10];
    const float* Lzb = (const float*)d_in[11];
    // d_in[12], d_in[13] (Lrw, Lrb) dead
    const float* Lhw = (const float*)d_in[14];
    const float* Lhb = (const float*)d_in[15];
    const float* W1  = (const float*)d_in[16];
    const float* b1  = (const float*)d_in[17];
    const float* W2  = (const float*)d_in[18];
    const float* b2  = (const float*)d_in[19];

    float* out = (float*)d_out;
    float* ws  = (float*)d_ws;

    int*    cnt   = (int*)(ws + OFF_CNT);
    float*  deg   = ws + OFF_DEG;
    float*  dinv  = ws + OFF_DINV;
    float*  Mz    = ws + OFF_MZ;
    float*  Mh    = ws + OFF_MH;
    float*  cz    = ws + OFF_CZ;
    float*  ch    = ws + OFF_CH;
    float*  probs = ws + OFF_PROBS;
    float*  W2T   = ws + OFF_W2T;
    float2* ell   = (float2*)(ws + OFF_ELL);
    float*  XT    = ws + OFF_XT;

    int useELL = (ws_size >= NEED_ELL) ? 1 : 0;
    int useXT  = (ws_size >= NEED_XT) ? 1 : 0;
    float* P = useELL ? (ws + OFF_P) : (ws + OFF_ELL);   // tier B reuses ELL space

    // zero cnt + deg
    hipMemsetAsync(ws, 0, (size_t)OFF_DINV * sizeof(float), stream);
    build_kernel<<<NB_E + (useXT ? NB_XT : 0), 256, 0, stream>>>(
        ei, ea, x, cnt, deg, ell, (float4*)XT, useELL, useXT);
    prep_kernel<<<NB_DINV + 2 + (useXT ? NB_XT : 0), 256, 0, stream>>>(
        deg, dinv, Wz, bz, Wh, bh, Lzw, Lzb, Lhw, Lhb, att, W2,
        Mz, Mh, cz, ch, probs, W2T, (float4*)XT);
    if (useELL) {
        gather_kernel<<<2 * NN * TP / 256, 256, 0, stream>>>(
            cnt, dinv, ell, (const float4*)XT, x, useXT, (float4*)P);
    } else {
        initP_kernel<<<(NN * TP + 255) / 256, 256, 0, stream>>>(x, dinv, (float4*)P);
        scatterB_kernel<<<(NE * FT + 255) / 256, 256, 0, stream>>>(ei, ea, dinv, x, P);
    }
    fused_kernel<<<NN / NPB, 512, 0, stream>>>((const float4*)P, Mz, Mh, cz, ch, probs,
                                               W1, b1, W2T, b2, out);
}